// Round 8
// baseline (186.542 us; speedup 1.0000x reference)
//
#include <hip/hip_runtime.h>
#include <cstdint>

typedef unsigned short u16;
typedef short s16x8 __attribute__((ext_vector_type(8)));
typedef short s16x4 __attribute__((ext_vector_type(4)));
typedef float f32x4 __attribute__((ext_vector_type(4)));

#define B_   4
#define T_   2048
#define C_   1024
#define H_   16
#define HD_  64
#define M_   8192      // B*T
#define N3_  3072      // 3*C

// 0.125 (1/sqrt(64)) * log2(e), folded into q at QKV-GEMM epilogue
#define QSCALE 0.18033688011112042f

// fp32 -> bf16 round-to-nearest-even
__device__ inline u16 f2b(float f) {
  union { float f; uint32_t u; } v; v.f = f;
  uint32_t u = v.u;
  return (u16)((u + 0x7FFFu + ((u >> 16) & 1u)) >> 16);
}

// pack 2 fp32 -> 2 bf16 in one dword (RNE): dst.lo = src0, dst.hi = src1
__device__ inline uint32_t cvtpk(float lo, float hi) {
  uint32_t r;
  asm("v_cvt_pk_bf16_f32 %0, %1, %2" : "=v"(r) : "v"(lo), "v"(hi));
  return r;
}

__device__ inline f32x4 mfma16(s16x4 a, s16x4 b, f32x4 c) {
#if __has_builtin(__builtin_amdgcn_mfma_f32_16x16x16bf16_1k)
  return __builtin_amdgcn_mfma_f32_16x16x16bf16_1k(a, b, c, 0, 0, 0);
#else
  f32x4 d;
  asm("v_mfma_f32_16x16x16_bf16 %0, %1, %2, %3"
      : "=v"(d) : "v"(a), "v"(b), "v"(c));
  return d;
#endif
}

// async global->LDS, 16B per lane (dest = wave-uniform base + lane*16)
__device__ inline void gload_lds16(const void* g, void* l) {
  __builtin_amdgcn_global_load_lds(
      (const __attribute__((address_space(1))) void*)g,
      (__attribute__((address_space(3))) void*)l, 16, 0, 0);
}

// ---------------- convert x (fp32) -> bf16, same layout ----------------
__global__ __launch_bounds__(256) void cvt_f32_bf16(
    const float* __restrict__ in, u16* __restrict__ out, int n) {
  int i = (blockIdx.x * 256 + threadIdx.x) * 8;
  if (i >= n) return;
  float4 a = *(const float4*)(in + i);
  float4 b = *(const float4*)(in + i + 4);
  s16x8 r;
  r[0] = (short)f2b(a.x); r[1] = (short)f2b(a.y);
  r[2] = (short)f2b(a.z); r[3] = (short)f2b(a.w);
  r[4] = (short)f2b(b.x); r[5] = (short)f2b(b.y);
  r[6] = (short)f2b(b.z); r[7] = (short)f2b(b.w);
  *(s16x8*)(out + i) = r;
}

// ------- transpose+convert: W fp32 [K][N] -> WT bf16 [N][K] ------------
__global__ __launch_bounds__(256) void cvt_transpose(
    const float* __restrict__ W, u16* __restrict__ WT, int K, int N) {
  __shared__ u16 tile[64][65];
  int n0 = blockIdx.x * 64, k0 = blockIdx.y * 64;
  int j = threadIdx.x & 63, i0 = threadIdx.x >> 6;  // j fast, i0 in 0..3
#pragma unroll
  for (int i = i0; i < 64; i += 4)
    tile[i][j] = f2b(W[(size_t)(k0 + i) * N + n0 + j]);
  __syncthreads();
#pragma unroll
  for (int i = i0; i < 64; i += 4)
    WT[(size_t)(n0 + i) * K + k0 + j] = tile[j][i];
}

// ---------------- GEMM: C[M][N] = A[M][K] * Bt[N][K]^T + bias ----------
// 2-barrier structure (measured-best), BK=64, 128x128 tile, 4 waves,
// 32 KB LDS. Chunk-XOR swizzle via pre-swizzled global source -> 0 conflicts.
// MODE 0: fp32 out.  MODE 1: scatter bf16 q,k->[B,H,T,64] (q pre-scaled),
//                            v -> transposed [B,H,64,T].
template <int MODE>
__global__ __launch_bounds__(256, 4) void gemm_bt(
    const u16* __restrict__ A, const u16* __restrict__ Bt,
    const float* __restrict__ bias, float* __restrict__ outf,
    u16* __restrict__ qo, u16* __restrict__ ko, u16* __restrict__ vo,
    int M, int N, int K) {
  __shared__ u16 As[128 * 64];   // 16 KB, rows 128B, chunk-swizzled
  __shared__ u16 Bs[128 * 64];   // 16 KB

  int nwg = gridDim.x;
  int bid0 = blockIdx.x;
  int bid = (bid0 & 7) * (nwg >> 3) + (bid0 >> 3);   // XCD swizzle (nwg%8==0)
  int nbn = N >> 7;
  int bm = bid / nbn, bn = bid % nbn;
  int m0 = bm * 128, n0 = bn * 128;
  int tid = threadIdx.x;
  int lane = tid & 63, w = tid >> 6;
  int wm = (w >> 1) * 64, wn = (w & 1) * 64;
  int l15 = lane & 15, g = lane >> 4;

  f32x4 acc[4][4] = {};

  for (int kb = 0; kb < K; kb += 64) {
    __syncthreads();  // all waves done reading previous tile
#pragma unroll
    for (int p = 0; p < 4; ++p) {
      int idx = p * 256 + tid;
      int row = idx >> 3, pc = idx & 7;
      int sc = (pc ^ (row & 7)) * 8;     // pre-swizzled source chunk
      gload_lds16(A  + (size_t)(m0 + row) * K + kb + sc, &As[idx * 8]);
      gload_lds16(Bt + (size_t)(n0 + row) * K + kb + sc, &Bs[idx * 8]);
    }
    __syncthreads();  // (compiler emits vmcnt(0) before barrier)

#pragma unroll
    for (int ks = 0; ks < 2; ++ks) {
      int ck = ((g + 4 * ks) ^ (l15 & 7)) * 8;   // swizzled read chunk
      s16x8 af[4], bf[4];
#pragma unroll
      for (int mi = 0; mi < 4; ++mi)
        af[mi] = *(const s16x8*)&As[(wm + mi * 16 + l15) * 64 + ck];
#pragma unroll
      for (int ni = 0; ni < 4; ++ni)
        bf[ni] = *(const s16x8*)&Bs[(wn + ni * 16 + l15) * 64 + ck];
#pragma unroll
      for (int mi = 0; mi < 4; ++mi)
#pragma unroll
        for (int ni = 0; ni < 4; ++ni)
          acc[mi][ni] = __builtin_amdgcn_mfma_f32_16x16x32_bf16(
              af[mi], bf[ni], acc[mi][ni], 0, 0, 0);
    }
  }

#pragma unroll
  for (int mi = 0; mi < 4; ++mi)
#pragma unroll
    for (int ni = 0; ni < 4; ++ni) {
      int col = n0 + wn + ni * 16 + l15;
      float bv = bias[col];
      int row0 = m0 + wm + mi * 16 + g * 4;  // C/D: col=lane&15, row=(lane>>4)*4+reg
      if (MODE == 0) {
#pragma unroll
        for (int r = 0; r < 4; ++r)
          outf[(size_t)(row0 + r) * N + col] = acc[mi][ni][r] + bv;
      } else {
        int which = col >> 10, hc = col & 1023;
        int h = hc >> 6, d = hc & 63;
        int b = row0 >> 11, t0 = row0 & 2047;
        if (which == 2) {
          s16x4 pv;
#pragma unroll
          for (int r = 0; r < 4; ++r) pv[r] = (short)f2b(acc[mi][ni][r] + bv);
          *(s16x4*)(vo + ((size_t)((b * 16 + h) * 64 + d)) * 2048 + t0) = pv;
        } else {
          u16* dst = (which == 0) ? qo : ko;
          float sc2 = (which == 0) ? QSCALE : 1.0f;
#pragma unroll
          for (int r = 0; r < 4; ++r)
            dst[(((size_t)(b * 16 + h)) * 2048 + (t0 + r)) * 64 + d] =
                f2b((acc[mi][ni][r] + bv) * sc2);
        }
      }
    }
}

// ---------------- flash attention, causal, bf16 MFMA, swapped QK^T -----
// grid: 64 (b,h) x 32 q-tiles of 64 rows; block 256 = 4 waves x 16 q-rows
// S^T = mfma(K, Q): lane holds one q-row (q=l15), 16 kv values in regs.
// PV as O^T = V^T * P^T via 16x16x16 mfma: P packed via v_cvt_pk_bf16_f32.
// Round-6 proven numerics (m=-3e30 init, shfl_xor reductions).
__global__ __launch_bounds__(256, 4) void attn_fwd(
    const u16* __restrict__ Q, const u16* __restrict__ Kg,
    const u16* __restrict__ Vt, u16* __restrict__ Y) {
  __shared__ u16 Ks[64 * 64];   // K tile  [kv][hd], 128B rows, swizzled
  __shared__ u16 Vs[64 * 64];   // V^T tile [hd][kv], 128B rows, swizzled

  int bid = blockIdx.x;
  int bh = bid & 63;
  int qt = 31 - (bid >> 6);       // big tiles first
  int tid = threadIdx.x, lane = tid & 63, w = tid >> 6;
  int l15 = lane & 15, g = lane >> 4;

  const u16* Qh = Q  + (size_t)bh * T_ * HD_;
  const u16* Kh = Kg + (size_t)bh * T_ * HD_;
  const u16* Vh = Vt + (size_t)bh * HD_ * T_;   // [64][2048]

  int q0 = qt * 64 + w * 16;      // wave's first q row
  int qrow = q0 + l15;            // THIS lane's q row

  s16x8 qa[2];
#pragma unroll
  for (int ks = 0; ks < 2; ++ks)
    qa[ks] = *(const s16x8*)(Qh + (size_t)qrow * HD_ + g * 8 + ks * 32);

  f32x4 oacc[4] = {};             // O^T: oacc[df][r] = O[q][df*16+g*4+r]
  float m = -3.0e30f, l = 0.f;

  // staging: thread stages rows sr and sr+32, 16B chunk sc
  int sr = tid >> 3, sc = tid & 7;
  int wswz = (sr & 7) << 4;       // write-side swizzle (same for sr+32)
  int rswz = (l15 & 7) << 4;      // read-side swizzle (rows = *16 + l15)
  char* KsB = (char*)Ks;
  char* VsB = (char*)Vs;

  // preload tile 0 into registers
  s16x8 kr0 = *(const s16x8*)(Kh + (size_t)sr * HD_ + sc * 8);
  s16x8 kr1 = *(const s16x8*)(Kh + (size_t)(sr + 32) * HD_ + sc * 8);
  s16x8 vr0 = *(const s16x8*)(Vh + (size_t)sr * T_ + sc * 8);
  s16x8 vr1 = *(const s16x8*)(Vh + (size_t)(sr + 32) * T_ + sc * 8);

  int ntile = qt + 1;
  for (int kt = 0; kt < ntile; ++kt) {
    int kvb = kt * 64;
    __syncthreads();              // previous tile's reads done
    *(s16x8*)(KsB + sr * 128 + ((sc * 16) ^ wswz))        = kr0;
    *(s16x8*)(KsB + (sr + 32) * 128 + ((sc * 16) ^ wswz)) = kr1;
    *(s16x8*)(VsB + sr * 128 + ((sc * 16) ^ wswz))        = vr0;
    *(s16x8*)(VsB + (sr + 32) * 128 + ((sc * 16) ^ wswz)) = vr1;
    __syncthreads();              // tile visible

    // T14: issue NEXT tile's global loads now; latency hides under compute
    {
      int kvn = (kt + 1 < ntile) ? (kt + 1) * 64 : 0;
      kr0 = *(const s16x8*)(Kh + (size_t)(kvn + sr) * HD_ + sc * 8);
      kr1 = *(const s16x8*)(Kh + (size_t)(kvn + sr + 32) * HD_ + sc * 8);
      vr0 = *(const s16x8*)(Vh + (size_t)sr * T_ + kvn + sc * 8);
      vr1 = *(const s16x8*)(Vh + (size_t)(sr + 32) * T_ + kvn + sc * 8);
    }

    // S^T = K Q^T  (D: col=q=l15, row=kv=cf*16+g*4+r)
    f32x4 sacc[4] = {};
    __builtin_amdgcn_s_setprio(1);
#pragma unroll
    for (int cf = 0; cf < 4; ++cf)
#pragma unroll
      for (int ks = 0; ks < 2; ++ks) {
        s16x8 kb = *(const s16x8*)(KsB + (cf * 16 + l15) * 128 +
                                   ((g * 16 + ks * 64) ^ rswz));
        sacc[cf] = __builtin_amdgcn_mfma_f32_16x16x32_bf16(kb, qa[ks], sacc[cf], 0, 0, 0);
      }
    __builtin_amdgcn_s_setprio(0);

    // causal mask (diag tile only); values in log2 domain (q pre-scaled)
    if (kt == qt) {
#pragma unroll
      for (int cf = 0; cf < 4; ++cf)
#pragma unroll
        for (int r = 0; r < 4; ++r) {
          int kv = kvb + cf * 16 + g * 4 + r;
          if (kv > qrow) sacc[cf][r] = -1e30f;
        }
    }

    // row max: tree over 16 in-register values + 2 cross-lane reduces
    float t0 = fmaxf(fmaxf(sacc[0][0], sacc[0][1]), fmaxf(sacc[0][2], sacc[0][3]));
    float t1 = fmaxf(fmaxf(sacc[1][0], sacc[1][1]), fmaxf(sacc[1][2], sacc[1][3]));
    float t2 = fmaxf(fmaxf(sacc[2][0], sacc[2][1]), fmaxf(sacc[2][2], sacc[2][3]));
    float t3 = fmaxf(fmaxf(sacc[3][0], sacc[3][1]), fmaxf(sacc[3][2], sacc[3][3]));
    float mx = fmaxf(fmaxf(t0, t1), fmaxf(t2, t3));
    mx = fmaxf(mx, __shfl_xor(mx, 16, 64));
    mx = fmaxf(mx, __shfl_xor(mx, 32, 64));

    // T13 defer-max: skip rescale while max grows < 8 (log2 domain)
    if (!__all(mx <= m + 8.0f)) {
      float mn = fmaxf(m, mx);
      float alpha = __builtin_amdgcn_exp2f(m - mn);
      m = mn;
      l *= alpha;
#pragma unroll
      for (int df = 0; df < 4; ++df)
#pragma unroll
        for (int r = 0; r < 4; ++r) oacc[df][r] *= alpha;
    }

    float rs = 0.f;
#pragma unroll
    for (int cf = 0; cf < 4; ++cf)
#pragma unroll
      for (int r = 0; r < 4; ++r) {
        float p = __builtin_amdgcn_exp2f(sacc[cf][r] - m);
        sacc[cf][r] = p;
        rs += p;
      }
    rs += __shfl_xor(rs, 16, 64);
    rs += __shfl_xor(rs, 32, 64);
    l += rs;

    // O^T += V^T P^T via 16x16x16: B = P^T packed in-reg (cvt_pk), A = V^T LDS
#pragma unroll
    for (int cf = 0; cf < 4; ++cf) {
      union { uint32_t u[2]; s16x4 v; } pk;
      pk.u[0] = cvtpk(sacc[cf][0], sacc[cf][1]);
      pk.u[1] = cvtpk(sacc[cf][2], sacc[cf][3]);
      __builtin_amdgcn_s_setprio(1);
#pragma unroll
      for (int df = 0; df < 4; ++df) {
        s16x4 va = *(const s16x4*)(VsB + (df * 16 + l15) * 128 +
                                   ((cf * 32 + g * 8) ^ rswz));
        oacc[df] = mfma16(va, pk.v, oacc[df]);
      }
      __builtin_amdgcn_s_setprio(0);
    }
  }

  // epilogue: Y[b][t][h*64 + d] bf16, 8B per store (d contiguous over r)
  int b = bh >> 4, h = bh & 15;
  float inv = 1.0f / l;
  u16* yrow = Y + ((size_t)b * T_ + qrow) * C_ + h * 64;
#pragma unroll
  for (int df = 0; df < 4; ++df) {
    union { uint32_t u[2]; s16x4 v; } pk;
    pk.u[0] = cvtpk(oacc[df][0] * inv, oacc[df][1] * inv);
    pk.u[1] = cvtpk(oacc[df][2] * inv, oacc[df][3] * inv);
    *(s16x4*)(yrow + df * 16 + g * 4) = pk.v;
  }
}

// ----------------------------- launcher --------------------------------
extern "C" void kernel_launch(void* const* d_in, const int* in_sizes, int n_in,
                              void* d_out, int out_size, void* d_ws, size_t ws_size,
                              hipStream_t stream) {
  const float* x      = (const float*)d_in[0];
  const float* w_attn = (const float*)d_in[1];
  const float* b_attn = (const float*)d_in[2];
  const float* w_proj = (const float*)d_in[3];
  const float* b_proj = (const float*)d_in[4];
  float* out = (float*)d_out;

  u16* ws  = (u16*)d_ws;
  u16* xb  = ws;                           // [8192][1024] bf16 (reused as ya)
  u16* wat = xb  + (size_t)M_ * C_;        // [3072][1024] bf16 (W_attn^T)
  u16* wpt = wat + (size_t)N3_ * C_;       // [1024][1024] bf16 (W_proj^T)
  u16* q   = wpt + (size_t)C_ * C_;        // [B,H,T,64] bf16 (pre-scaled)
  u16* k   = q   + (size_t)M_ * C_;        // [B,H,T,64] bf16
  u16* v   = k   + (size_t)M_ * C_;        // [B,H,64,T] bf16 (TRANSPOSED)
  u16* ya  = xb;                           // reuse: xb dead after QKV GEMM

  cvt_f32_bf16<<<dim3((M_ * C_) / (256 * 8)), dim3(256), 0, stream>>>(x, xb, M_ * C_);
  cvt_transpose<<<dim3(N3_ / 64, C_ / 64), dim3(256), 0, stream>>>(w_attn, wat, C_, N3_);
  cvt_transpose<<<dim3(C_ / 64, C_ / 64), dim3(256), 0, stream>>>(w_proj, wpt, C_, C_);

  gemm_bt<1><<<dim3((M_ / 128) * (N3_ / 128)), dim3(256), 0, stream>>>(
      xb, wat, b_attn, nullptr, q, k, v, M_, N3_, C_);

  attn_fwd<<<dim3(64 * 32), dim3(256), 0, stream>>>(q, k, v, ya);

  gemm_bt<0><<<dim3((M_ / 128) * (C_ / 128)), dim3(256), 0, stream>>>(
      ya, wpt, b_proj, out, nullptr, nullptr, nullptr, M_, C_, C_);
}

// Round 10
// 166.466 us; speedup vs baseline: 1.1206x; 1.1206x over previous
//
#include <hip/hip_runtime.h>
#include <cstdint>

typedef unsigned short u16;
typedef short s16x8 __attribute__((ext_vector_type(8)));
typedef short s16x4 __attribute__((ext_vector_type(4)));
typedef float f32x4 __attribute__((ext_vector_type(4)));
typedef float f32x16 __attribute__((ext_vector_type(16)));

#define B_   4
#define T_   2048
#define C_   1024
#define H_   16
#define HD_  64
#define M_   8192      // B*T
#define N3_  3072      // 3*C

// 0.125 (1/sqrt(64)) * log2(e), folded into q at QKV-GEMM epilogue
#define QSCALE 0.18033688011112042f

// fp32 -> bf16 round-to-nearest-even
__device__ inline u16 f2b(float f) {
  union { float f; uint32_t u; } v; v.f = f;
  uint32_t u = v.u;
  return (u16)((u + 0x7FFFu + ((u >> 16) & 1u)) >> 16);
}

// pack 2 fp32 -> 2 bf16 in one dword (RNE): dst.lo = src0, dst.hi = src1
__device__ inline uint32_t cvtpk(float lo, float hi) {
  uint32_t r;
  asm("v_cvt_pk_bf16_f32 %0, %1, %2" : "=v"(r) : "v"(lo), "v"(hi));
  return r;
}

// async global->LDS, 16B per lane (dest = wave-uniform base + lane*16)
__device__ inline void gload_lds16(const void* g, void* l) {
  __builtin_amdgcn_global_load_lds(
      (const __attribute__((address_space(1))) void*)g,
      (__attribute__((address_space(3))) void*)l, 16, 0, 0);
}

// ---------------- convert x (fp32) -> bf16, same layout ----------------
__global__ __launch_bounds__(256) void cvt_f32_bf16(
    const float* __restrict__ in, u16* __restrict__ out, int n) {
  int i = (blockIdx.x * 256 + threadIdx.x) * 8;
  if (i >= n) return;
  float4 a = *(const float4*)(in + i);
  float4 b = *(const float4*)(in + i + 4);
  s16x8 r;
  r[0] = (short)f2b(a.x); r[1] = (short)f2b(a.y);
  r[2] = (short)f2b(a.z); r[3] = (short)f2b(a.w);
  r[4] = (short)f2b(b.x); r[5] = (short)f2b(b.y);
  r[6] = (short)f2b(b.z); r[7] = (short)f2b(b.w);
  *(s16x8*)(out + i) = r;
}

// ------- transpose+convert: W fp32 [K][N] -> WT bf16 [N][K] ------------
__global__ __launch_bounds__(256) void cvt_transpose(
    const float* __restrict__ W, u16* __restrict__ WT, int K, int N) {
  __shared__ u16 tile[64][65];
  int n0 = blockIdx.x * 64, k0 = blockIdx.y * 64;
  int j = threadIdx.x & 63, i0 = threadIdx.x >> 6;  // j fast, i0 in 0..3
#pragma unroll
  for (int i = i0; i < 64; i += 4)
    tile[i][j] = f2b(W[(size_t)(k0 + i) * N + n0 + j]);
  __syncthreads();
#pragma unroll
  for (int i = i0; i < 64; i += 4)
    WT[(size_t)(n0 + i) * K + k0 + j] = tile[j][i];
}

// ---------------- GEMM: C[M][N] = A[M][K] * Bt[N][K]^T + bias ----------
// 2-barrier structure (measured-best), BK=64, 128x128 tile, 4 waves,
// 32 KB LDS. Chunk-XOR swizzle via pre-swizzled global source -> 0 conflicts.
// MODE 0: fp32 out.  MODE 1: scatter bf16 q,k->[B,H,T,64] (q pre-scaled),
//                            v -> transposed [B,H,64,T].
template <int MODE>
__global__ __launch_bounds__(256, 4) void gemm_bt(
    const u16* __restrict__ A, const u16* __restrict__ Bt,
    const float* __restrict__ bias, float* __restrict__ outf,
    u16* __restrict__ qo, u16* __restrict__ ko, u16* __restrict__ vo,
    int M, int N, int K) {
  __shared__ u16 As[128 * 64];   // 16 KB, rows 128B, chunk-swizzled
  __shared__ u16 Bs[128 * 64];   // 16 KB

  int nwg = gridDim.x;
  int bid0 = blockIdx.x;
  int bid = (bid0 & 7) * (nwg >> 3) + (bid0 >> 3);   // XCD swizzle (nwg%8==0)
  int nbn = N >> 7;
  int bm = bid / nbn, bn = bid % nbn;
  int m0 = bm * 128, n0 = bn * 128;
  int tid = threadIdx.x;
  int lane = tid & 63, w = tid >> 6;
  int wm = (w >> 1) * 64, wn = (w & 1) * 64;
  int l15 = lane & 15, g = lane >> 4;

  f32x4 acc[4][4] = {};

  for (int kb = 0; kb < K; kb += 64) {
    __syncthreads();  // all waves done reading previous tile
#pragma unroll
    for (int p = 0; p < 4; ++p) {
      int idx = p * 256 + tid;
      int row = idx >> 3, pc = idx & 7;
      int sc = (pc ^ (row & 7)) * 8;     // pre-swizzled source chunk
      gload_lds16(A  + (size_t)(m0 + row) * K + kb + sc, &As[idx * 8]);
      gload_lds16(Bt + (size_t)(n0 + row) * K + kb + sc, &Bs[idx * 8]);
    }
    __syncthreads();  // (compiler emits vmcnt(0) before barrier)

#pragma unroll
    for (int ks = 0; ks < 2; ++ks) {
      int ck = ((g + 4 * ks) ^ (l15 & 7)) * 8;   // swizzled read chunk
      s16x8 af[4], bf[4];
#pragma unroll
      for (int mi = 0; mi < 4; ++mi)
        af[mi] = *(const s16x8*)&As[(wm + mi * 16 + l15) * 64 + ck];
#pragma unroll
      for (int ni = 0; ni < 4; ++ni)
        bf[ni] = *(const s16x8*)&Bs[(wn + ni * 16 + l15) * 64 + ck];
#pragma unroll
      for (int mi = 0; mi < 4; ++mi)
#pragma unroll
        for (int ni = 0; ni < 4; ++ni)
          acc[mi][ni] = __builtin_amdgcn_mfma_f32_16x16x32_bf16(
              af[mi], bf[ni], acc[mi][ni], 0, 0, 0);
    }
  }

#pragma unroll
  for (int mi = 0; mi < 4; ++mi)
#pragma unroll
    for (int ni = 0; ni < 4; ++ni) {
      int col = n0 + wn + ni * 16 + l15;
      float bv = bias[col];
      int row0 = m0 + wm + mi * 16 + g * 4;  // C/D: col=lane&15, row=(lane>>4)*4+reg
      if (MODE == 0) {
#pragma unroll
        for (int r = 0; r < 4; ++r)
          outf[(size_t)(row0 + r) * N + col] = acc[mi][ni][r] + bv;
      } else {
        int which = col >> 10, hc = col & 1023;
        int h = hc >> 6, d = hc & 63;
        int b = row0 >> 11, t0 = row0 & 2047;
        if (which == 2) {
          s16x4 pv;
#pragma unroll
          for (int r = 0; r < 4; ++r) pv[r] = (short)f2b(acc[mi][ni][r] + bv);
          *(s16x4*)(vo + ((size_t)((b * 16 + h) * 64 + d)) * 2048 + t0) = pv;
        } else {
          u16* dst = (which == 0) ? qo : ko;
          float sc2 = (which == 0) ? QSCALE : 1.0f;
#pragma unroll
          for (int r = 0; r < 4; ++r)
            dst[(((size_t)(b * 16 + h)) * 2048 + (t0 + r)) * 64 + d] =
                f2b((acc[mi][ni][r] + bv) * sc2);
        }
      }
    }
}

// ---------------- flash attention, causal, 32x32 MFMA, swapped QK^T ----
// grid: 64 (b,h) x 16 q-tiles of 128 rows; block 256 = 4 waves x 32 q-rows
// S^T = mfma32(K, Q): lane holds one q-row (q=lane&31), 32 kv vals in regs
// (16 per kv-32-block; partner lane^32 holds the other 16 rows).
// PV as O^T = V^T * P^T via 32x32x16: P stays in-register; the B-fragment
// redistribution uses cvt_pk + send-select shfl_xor(32) + cndmask (all
// verified primitives; permlane asm from r9 removed — suspect semantics).
// Per-q LDS traffic ~2x lower than the 16x16 version (32-row fragments).
__global__ __launch_bounds__(256, 3) void attn_fwd(
    const u16* __restrict__ Q, const u16* __restrict__ Kg,
    const u16* __restrict__ Vt, u16* __restrict__ Y) {
  __shared__ u16 Ks[64 * 64];   // K tile  [kv][hd], 128B rows, swizzled
  __shared__ u16 Vs[64 * 64];   // V^T tile [hd][kv], 128B rows, swizzled

  int bid = blockIdx.x;
  int bh = bid & 63;
  int qb = 15 - (bid >> 6);       // big tiles first
  int tid = threadIdx.x, lane = tid & 63, w = tid >> 6;
  int l31 = lane & 31, half = lane >> 5;

  const u16* Qh = Q  + (size_t)bh * T_ * HD_;
  const u16* Kh = Kg + (size_t)bh * T_ * HD_;
  const u16* Vh = Vt + (size_t)bh * HD_ * T_;   // [64][2048]

  int q0 = qb * 128;
  int qw = q0 + w * 32;           // wave's first q row
  int qrow = qw + l31;            // THIS lane's q row

  // Q in registers: 4 k-steps x 16B (k = kst*16 + half*8 + e)
  s16x8 qa[4];
#pragma unroll
  for (int kst = 0; kst < 4; ++kst)
    qa[kst] = *(const s16x8*)(Qh + (size_t)qrow * HD_ + kst * 16 + half * 8);

  f32x16 oacc[2] = {};            // O^T: [hb] -> hd = hb*32+(r&3)+8(r>>2)+4*half
  float m = -3.0e30f, l = 0.f;

  // staging: thread stages rows sr and sr+32, 16B chunk sc
  int sr = tid >> 3, sc = tid & 7;
  int wswz = (sr & 7) << 4;       // write-side swizzle (same for sr+32)
  int rswz = (l31 & 7) << 4;      // read-side swizzle (rows = base + l31)
  char* KsB = (char*)Ks;
  char* VsB = (char*)Vs;

  // preload tile 0 into registers
  s16x8 kr0 = *(const s16x8*)(Kh + (size_t)sr * HD_ + sc * 8);
  s16x8 kr1 = *(const s16x8*)(Kh + (size_t)(sr + 32) * HD_ + sc * 8);
  s16x8 vr0 = *(const s16x8*)(Vh + (size_t)sr * T_ + sc * 8);
  s16x8 vr1 = *(const s16x8*)(Vh + (size_t)(sr + 32) * T_ + sc * 8);

  int ntile = 2 * qb + 2;
  for (int kt = 0; kt < ntile; ++kt) {
    int kvb = kt * 64;
    __syncthreads();              // previous tile's reads done
    *(s16x8*)(KsB + sr * 128 + ((sc * 16) ^ wswz))        = kr0;
    *(s16x8*)(KsB + (sr + 32) * 128 + ((sc * 16) ^ wswz)) = kr1;
    *(s16x8*)(VsB + sr * 128 + ((sc * 16) ^ wswz))        = vr0;
    *(s16x8*)(VsB + (sr + 32) * 128 + ((sc * 16) ^ wswz)) = vr1;
    __syncthreads();              // tile visible

    // T14: issue NEXT tile's global loads now; latency hides under compute
    {
      int kvn = (kt + 1 < ntile) ? (kt + 1) * 64 : 0;
      kr0 = *(const s16x8*)(Kh + (size_t)(kvn + sr) * HD_ + sc * 8);
      kr1 = *(const s16x8*)(Kh + (size_t)(kvn + sr + 32) * HD_ + sc * 8);
      vr0 = *(const s16x8*)(Vh + (size_t)sr * T_ + kvn + sc * 8);
      vr1 = *(const s16x8*)(Vh + (size_t)(sr + 32) * T_ + kvn + sc * 8);
    }

    // wave-level skip of fully-masked tiles (barriers stay block-uniform)
    if (kvb > qw + 31) continue;

    // S^T = K Q^T per kv-32-block (D: col=q=l31, row=kv=(r&3)+8(r>>2)+4*half)
    f32x16 s0 = {}, s1 = {};
    __builtin_amdgcn_s_setprio(1);
#pragma unroll
    for (int kst = 0; kst < 4; ++kst) {
      s16x8 kb0 = *(const s16x8*)(KsB +
          (((l31) * 128 + kst * 32 + half * 16) ^ rswz));
      s0 = __builtin_amdgcn_mfma_f32_32x32x16_bf16(kb0, qa[kst], s0, 0, 0, 0);
      s16x8 kb1 = *(const s16x8*)(KsB +
          (((32 + l31) * 128 + kst * 32 + half * 16) ^ rswz));
      s1 = __builtin_amdgcn_mfma_f32_32x32x16_bf16(kb1, qa[kst], s1, 0, 0, 0);
    }
    __builtin_amdgcn_s_setprio(0);

    // causal mask (only tiles that can cross the diagonal for this wave)
    if (kvb + 63 > qw) {
#pragma unroll
      for (int r = 0; r < 16; ++r) {
        int kv0 = kvb + (r & 3) + 8 * (r >> 2) + 4 * half;
        if (kv0 > qrow) s0[r] = -1e30f;
        if (kv0 + 32 > qrow) s1[r] = -1e30f;
      }
    }

    // row max: in-lane tree over 32 values + ONE cross-lane combine (^32)
    float a0 = fmaxf(fmaxf(s0[0], s0[1]), fmaxf(s0[2], s0[3]));
    float a1 = fmaxf(fmaxf(s0[4], s0[5]), fmaxf(s0[6], s0[7]));
    float a2 = fmaxf(fmaxf(s0[8], s0[9]), fmaxf(s0[10], s0[11]));
    float a3 = fmaxf(fmaxf(s0[12], s0[13]), fmaxf(s0[14], s0[15]));
    float a4 = fmaxf(fmaxf(s1[0], s1[1]), fmaxf(s1[2], s1[3]));
    float a5 = fmaxf(fmaxf(s1[4], s1[5]), fmaxf(s1[6], s1[7]));
    float a6 = fmaxf(fmaxf(s1[8], s1[9]), fmaxf(s1[10], s1[11]));
    float a7 = fmaxf(fmaxf(s1[12], s1[13]), fmaxf(s1[14], s1[15]));
    float mx = fmaxf(fmaxf(fmaxf(a0, a1), fmaxf(a2, a3)),
                     fmaxf(fmaxf(a4, a5), fmaxf(a6, a7)));
    mx = fmaxf(mx, __shfl_xor(mx, 32, 64));

    // T13 defer-max: skip rescale while max grows < 8 (log2 domain)
    if (!__all(mx <= m + 8.0f)) {
      float mn = fmaxf(m, mx);
      float alpha = __builtin_amdgcn_exp2f(m - mn);
      m = mn;
      l *= alpha;
#pragma unroll
      for (int i = 0; i < 16; ++i) { oacc[0][i] *= alpha; oacc[1][i] *= alpha; }
    }

    float rs = 0.f;
#pragma unroll
    for (int r = 0; r < 16; ++r) {
      float p0 = __builtin_amdgcn_exp2f(s0[r] - m);
      float p1 = __builtin_amdgcn_exp2f(s1[r] - m);
      s0[r] = p0; s1[r] = p1;
      rs += p0 + p1;
    }
    rs += __shfl_xor(rs, 32, 64);
    l += rs;

    // P^T B-fragments: lane (l31,half) needs kv = ks4*16 + half*8 + {0..7}
    // within window W = 32*(ks4>>1) + 16*(ks4&1). Held dword pairs (kv_off):
    //   own A0,A1 = 4*half+{0..3};  own B0,B1 = 8+4*half+{0..3}.
    // half=0 wants {0..7} = ownA ++ partnerA; half=1 wants {8..15} =
    // partnerB ++ ownB. Send-select: shfl(half?A:B) delivers exactly the
    // partner dwords each half needs.
    s16x8 pb[4];
#pragma unroll
    for (int ks4 = 0; ks4 < 4; ++ks4) {
      const f32x16& sv = (ks4 < 2) ? s0 : s1;
      const int R = (ks4 & 1) * 8;
      uint32_t A0 = cvtpk(sv[R + 0], sv[R + 1]);
      uint32_t A1 = cvtpk(sv[R + 2], sv[R + 3]);
      uint32_t B0 = cvtpk(sv[R + 4], sv[R + 5]);
      uint32_t B1 = cvtpk(sv[R + 6], sv[R + 7]);
      uint32_t r0 = (uint32_t)__shfl_xor((int)(half ? A0 : B0), 32, 64);
      uint32_t r1 = (uint32_t)__shfl_xor((int)(half ? A1 : B1), 32, 64);
      union { uint32_t u[4]; s16x8 v; } pk_;
      pk_.u[0] = half ? r0 : A0;   // kv_off 0,1   | 8,9
      pk_.u[1] = half ? r1 : A1;   // kv_off 2,3   | 10,11
      pk_.u[2] = half ? B0 : r0;   // kv_off 4,5   | 12,13
      pk_.u[3] = half ? B1 : r1;   // kv_off 6,7   | 14,15
      pb[ks4] = pk_.v;
    }

    // O^T += V^T P^T: A = V^T fragment (b128), B = pb (in regs)
    __builtin_amdgcn_s_setprio(1);
#pragma unroll
    for (int hb = 0; hb < 2; ++hb)
#pragma unroll
      for (int ks4 = 0; ks4 < 4; ++ks4) {
        s16x8 va = *(const s16x8*)(VsB +
            (((hb * 32 + l31) * 128 + ks4 * 32 + half * 16) ^ rswz));
        oacc[hb] = __builtin_amdgcn_mfma_f32_32x32x16_bf16(va, pb[ks4],
                                                           oacc[hb], 0, 0, 0);
      }
    __builtin_amdgcn_s_setprio(0);
  }

  // epilogue: Y[b][q][h*64 + hd], hd = hb*32 + rg*8 + half*4 + i
  int b = bh >> 4, h = bh & 15;
  float inv = 1.0f / l;
  u16* yrow = Y + ((size_t)b * T_ + qrow) * C_ + h * 64;
#pragma unroll
  for (int hb = 0; hb < 2; ++hb)
#pragma unroll
    for (int rg = 0; rg < 4; ++rg) {
      union { uint32_t u[2]; s16x4 v; } o;
      o.u[0] = cvtpk(oacc[hb][rg * 4 + 0] * inv, oacc[hb][rg * 4 + 1] * inv);
      o.u[1] = cvtpk(oacc[hb][rg * 4 + 2] * inv, oacc[hb][rg * 4 + 3] * inv);
      *(s16x4*)(yrow + hb * 32 + rg * 8 + half * 4) = o.v;
    }
}

// ----------------------------- launcher --------------------------------
extern "C" void kernel_launch(void* const* d_in, const int* in_sizes, int n_in,
                              void* d_out, int out_size, void* d_ws, size_t ws_size,
                              hipStream_t stream) {
  const float* x      = (const float*)d_in[0];
  const float* w_attn = (const float*)d_in[1];
  const float* b_attn = (const float*)d_in[2];
  const float* w_proj = (const float*)d_in[3];
  const float* b_proj = (const float*)d_in[4];
  float* out = (float*)d_out;

  u16* ws  = (u16*)d_ws;
  u16* xb  = ws;                           // [8192][1024] bf16 (reused as ya)
  u16* wat = xb  + (size_t)M_ * C_;        // [3072][1024] bf16 (W_attn^T)
  u16* wpt = wat + (size_t)N3_ * C_;       // [1024][1024] bf16 (W_proj^T)
  u16* q   = wpt + (size_t)C_ * C_;        // [B,H,T,64] bf16 (pre-scaled)
  u16* k   = q   + (size_t)M_ * C_;        // [B,H,T,64] bf16
  u16* v   = k   + (size_t)M_ * C_;        // [B,H,64,T] bf16 (TRANSPOSED)
  u16* ya  = xb;                           // reuse: xb dead after QKV GEMM

  cvt_f32_bf16<<<dim3((M_ * C_) / (256 * 8)), dim3(256), 0, stream>>>(x, xb, M_ * C_);
  cvt_transpose<<<dim3(N3_ / 64, C_ / 64), dim3(256), 0, stream>>>(w_attn, wat, C_, N3_);
  cvt_transpose<<<dim3(C_ / 64, C_ / 64), dim3(256), 0, stream>>>(w_proj, wpt, C_, C_);

  gemm_bt<1><<<dim3((M_ / 128) * (N3_ / 128)), dim3(256), 0, stream>>>(
      xb, wat, b_attn, nullptr, q, k, v, M_, N3_, C_);

  attn_fwd<<<dim3(64 * 16), dim3(256), 0, stream>>>(q, k, v, ya);

  gemm_bt<0><<<dim3((M_ / 128) * (C_ / 128)), dim3(256), 0, stream>>>(
      ya, wpt, b_proj, out, nullptr, nullptr, nullptr, M_, C_, C_);
}